// Round 11
// baseline (298.069 us; speedup 1.0000x reference)
//
#include <hip/hip_runtime.h>
#include <math.h>

#define SEQ 50
#define UNITD 46
#define NEGBIG 1000000000000.0f

typedef _Float16 f16;
typedef f16 f16x4 __attribute__((ext_vector_type(4)));
typedef f16 f16x8 __attribute__((ext_vector_type(8)));
typedef float f32x4 __attribute__((ext_vector_type(4)));
typedef unsigned u32x2 __attribute__((ext_vector_type(2)));
typedef unsigned u32x4 __attribute__((ext_vector_type(4)));

__device__ __forceinline__ float rcpf(float x) { return __builtin_amdgcn_rcpf(x); }
__device__ __forceinline__ unsigned pk2(float lo, float hi) {
    return __builtin_bit_cast(unsigned, __builtin_amdgcn_cvt_pkrtz(lo, hi));
}

// ---- per-batch arena (bytes), shared by 2 cooperating waves ----
// [0,6400)      P tile [50][128B] swizzled; Q/K overlay it early; out tile reuses it
// [6400,12544)  V^T [48][128B] swizzled (row=u, col=seq)
// [12544,12800) M [64] f32 (mask, zero-padded)
#define ARENA 12800
#define QOFF 0
#define KOFF 2560
#define VOFF 6400
#define MOFF 12544

__device__ __forceinline__ int swzP(int row, int colbyte) {
    return row * 128 + (colbyte ^ ((row & 7) << 4));
}
__device__ __forceinline__ int swzV(int row, int colbyte) {
    return VOFF + row * 128 + (colbyte ^ ((row & 7) << 4));
}

// ---- ws layout ----
// f16x8 units [0,512): Wi B-frags; [512,896): Wo A-frags  (bytes [0,14336))
// bytes [14336,22528): rope table float2[64*16] = (cos*0.5, sgn*sin*0.5)
#define WS_ROPE 14336

__global__ void prep_kernel(const float* __restrict__ Wi,
                            const float* __restrict__ Wo,
                            char* __restrict__ ws)
{
    f16x8* wf = (f16x8*)ws;
    const int lane = threadIdx.x & 63;
    const int g = lane >> 4, t = lane & 15;
    #pragma unroll
    for (int nt = 0; nt < 4; ++nt) {
        int c = t + 16 * nt; bool cok = c < 62;
        const float* wr = Wi + (size_t)(UNITD + (cok ? c : 0)) * UNITD;
        #pragma unroll
        for (int kt = 0; kt < 2; ++kt) {
            f16x8 f;
            #pragma unroll
            for (int jj = 0; jj < 8; ++jj) {
                int u = 32 * kt + 8 * g + jj;
                f[jj] = (f16)((cok && u < UNITD) ? wr[u] : 0.f);
            }
            wf[(nt * 2 + kt) * 64 + lane] = f;
        }
    }
    #pragma unroll
    for (int mo = 0; mo < 3; ++mo) {
        int o = 16 * mo + t; bool ook = o < UNITD;
        const float* wr = Wo + (size_t)(ook ? o : 0) * UNITD;
        #pragma unroll
        for (int kt = 0; kt < 2; ++kt) {
            f16x8 f;
            #pragma unroll
            for (int jj = 0; jj < 8; ++jj) {
                int u = 32 * kt + 8 * g + jj;
                f[jj] = (f16)((ook && u < UNITD) ? wr[u] : 0.f);
            }
            wf[512 + (mo * 2 + kt) * 64 + lane] = f;
        }
    }
    // RoPE table (0.25 QK-scale baked as 0.5 per side); sgn=+1 d odd, -1 d even
    {
        float2* rt = (float2*)(ws + WS_ROPE);
        int seq = threadIdx.x;     // 0..63
        #pragma unroll
        for (int d = 0; d < 16; ++d) {
            float ang = (float)seq * expf(-(float)(d >> 1) * 1.1512925464970229f);
            float sn, cs;
            sincosf(ang, &sn, &cs);
            float2 v; v.x = cs * 0.5f; v.y = ((d & 1) ? sn : -sn) * 0.5f;
            rt[seq * 16 + d] = v;
        }
    }
}

// 4 waves/block: 2 batches, 2 waves per batch (wave w owns rows [32w,32w+32))
__global__ __launch_bounds__(256, 6) void gau_kernel(
    const float* __restrict__ x,
    const float* __restrict__ mask,
    const char* __restrict__ ws,
    const float* __restrict__ bi,
    const float* __restrict__ bo,
    const float* __restrict__ sq,
    const float* __restrict__ oq,
    const float* __restrict__ sk,
    const float* __restrict__ ok,
    const float* __restrict__ Wq,
    const float* __restrict__ bq,
    float* __restrict__ out,
    int Btot)
{
    const int lane = threadIdx.x & 63;
    const int wid  = threadIdx.x >> 6;      // 0..3
    const int pr_  = wid >> 1;              // batch pair slot 0..1
    const int w    = wid & 1;               // wave-in-pair 0..1
    const int b    = blockIdx.x * 2 + pr_;
    const int g    = lane >> 4;
    const int t    = lane & 15;

    const f16x8* wf = (const f16x8*)ws;

    __shared__ __align__(16) char smem[2 * ARENA];
    __shared__ float xmx[2][2], xsm[2][2];
    __shared__ __align__(16) float xz[2][2][48];
    char* wa = smem + pr_ * ARENA;
    float* M = (float*)(wa + MOFF);

    const bool bok = (b < Btot);            // grid is exact for B=32768; keep safe

    if (bok && w == 0)
        M[lane] = (lane < SEQ) ? mask[(size_t)b * SEQ + lane] : 0.f;

    // ================= phase B: h = silu(x @ Wi[46:108]^T + bi), rows [32w,32w+32) ====
    f16x8 bfW[4][2];
    float biv[4];
    #pragma unroll
    for (int nt = 0; nt < 4; ++nt) {
        int c = t + 16 * nt;
        biv[nt] = (c < 62) ? bi[UNITD + c] : 0.f;
        #pragma unroll
        for (int kt = 0; kt < 2; ++kt)
            bfW[nt][kt] = wf[(nt * 2 + kt) * 64 + lane];
    }

    f32x4 hB[2][4];
    #pragma unroll
    for (int mt2 = 0; mt2 < 2; ++mt2)
        #pragma unroll
        for (int nt = 0; nt < 4; ++nt) {
            f32x4 c; c[0] = biv[nt]; c[1] = biv[nt]; c[2] = biv[nt]; c[3] = biv[nt];
            hB[mt2][nt] = c;
        }

    if (bok) {
        const float* xb = x + (size_t)b * (SEQ * UNITD);
        #pragma unroll
        for (int mt2 = 0; mt2 < 2; ++mt2) {
            int mt = 2 * w + mt2;
            int row = 16 * mt + t; if (row > SEQ - 1) row = SEQ - 1;
            const float* xr = xb + row * UNITD;
            #pragma unroll
            for (int kt = 0; kt < 2; ++kt) {
                u32x4 axw;
                #pragma unroll
                for (int jj2 = 0; jj2 < 4; ++jj2) {
                    int u = 32 * kt + 8 * g + 2 * jj2;
                    float lo = 0.f, hi = 0.f;
                    if (u < UNITD) { float2 ww = *(const float2*)(xr + u); lo = ww.x; hi = ww.y; }
                    axw[jj2] = pk2(lo, hi);
                }
                f16x8 ax = __builtin_bit_cast(f16x8, axw);
                #pragma unroll
                for (int nt = 0; nt < 4; ++nt)
                    hB[mt2][nt] = __builtin_amdgcn_mfma_f32_16x16x32_f16(ax, bfW[nt][kt], hB[mt2][nt], 0, 0, 0);
            }
        }

        // ---- silu; v -> V^T LDS (own seq cols); qk channels kept in regs ----
        float qkv[2][4];
        #pragma unroll
        for (int mt2 = 0; mt2 < 2; ++mt2) {
            int mt = 2 * w + mt2;
            float s2[4], s3[4];
            #pragma unroll
            for (int nt = 0; nt < 4; ++nt) {
                float sl[4];
                #pragma unroll
                for (int r = 0; r < 4; ++r) {
                    float h = hB[mt2][nt][r];
                    sl[r] = h * rcpf(1.f + __expf(-h));
                }
                int ucol = t + 16 * nt;
                if (nt < 3 && ucol < UNITD) {
                    int seqb = 16 * mt + 4 * g;
                    float v0 = (seqb + 0 < SEQ) ? sl[0] : 0.f;
                    float v1 = (seqb + 1 < SEQ) ? sl[1] : 0.f;
                    float v2 = (seqb + 2 < SEQ) ? sl[2] : 0.f;
                    float v3 = (seqb + 3 < SEQ) ? sl[3] : 0.f;
                    u32x2 pw; pw[0] = pk2(v0, v1); pw[1] = pk2(v2, v3);
                    *(f16x4*)(wa + swzV(ucol, seqb * 2)) = __builtin_bit_cast(f16x4, pw);
                }
                if (nt == 2) { s2[0]=sl[0]; s2[1]=sl[1]; s2[2]=sl[2]; s2[3]=sl[3]; }
                if (nt == 3) { s3[0]=sl[0]; s3[1]=sl[1]; s3[2]=sl[2]; s3[3]=sl[3]; }
            }
            #pragma unroll
            for (int r = 0; r < 4; ++r) qkv[mt2][r] = (t >= 14) ? s2[r] : s3[r];
        }

        // ---- RoPE via table; q,k rows [32w,32w+32) -> LDS (overlaying P region) ----
        {
            f16* Q = (f16*)(wa + QOFF);
            f16* K = (f16*)(wa + KOFF);
            const float2* rt = (const float2*)(ws + WS_ROPE);
            int d = (t >= 14) ? (t - 14) : (t + 2);
            float sqd = sq[d], oqd = oq[d], skd = sk[d], okd = ok[d];
            #pragma unroll
            for (int mt2 = 0; mt2 < 2; ++mt2) {
                int mt = 2 * w + mt2;
                #pragma unroll
                for (int r = 0; r < 4; ++r) {
                    int seq = 16 * mt + 4 * g + r;
                    float2 cn = rt[seq * 16 + d];
                    float qv = qkv[mt2][r] * sqd + oqd;
                    float kv = qkv[mt2][r] * skd + okd;
                    float qp = __shfl_xor(qv, 1);
                    float kp = __shfl_xor(kv, 1);
                    Q[seq * 20 + d] = (f16)(qv * cn.x + qp * cn.y);
                    K[seq * 20 + d] = (f16)(kv * cn.x + kp * cn.y);
                }
            }
        }
    }

    __syncthreads();                                        // #1: K,V,Q,M staged

    // ================= phase D: P^T = q'k'^T, masked, softmax (own n4-half) ========
    f16x4 ak[4], bq_[2];
    #pragma unroll
    for (int m4 = 0; m4 < 4; ++m4) ak[m4] = *(f16x4*)(wa + KOFF + (16 * m4 + t) * 40 + 8 * g);
    #pragma unroll
    for (int n42 = 0; n42 < 2; ++n42)
        bq_[n42] = *(f16x4*)(wa + QOFF + (16 * (2 * w + n42) + t) * 40 + 8 * g);

    f32x4 pT[4][2];
    #pragma unroll
    for (int m4 = 0; m4 < 4; ++m4)
        #pragma unroll
        for (int n42 = 0; n42 < 2; ++n42) {
            f32x4 z; z[0]=0.f; z[1]=0.f; z[2]=0.f; z[3]=0.f;
            pT[m4][n42] = __builtin_amdgcn_mfma_f32_16x16x16f16(ak[m4], bq_[n42], z, 0, 0, 0);
        }

    f32x4 mj4[4];
    float NBv[4][4];
    #pragma unroll
    for (int m4 = 0; m4 < 4; ++m4) {
        mj4[m4] = *(f32x4*)(M + 16 * m4 + 4 * g);
        #pragma unroll
        for (int r = 0; r < 4; ++r)
            NBv[m4][r] = fmaf(mj4[m4][r], NEGBIG, -NEGBIG);
    }

    __syncthreads();                                        // #2: Q/K reads done, P writes may begin

    if (bok) {
        #pragma unroll
        for (int n42 = 0; n42 < 2; ++n42) {
            float a_[4][4];
            #pragma unroll
            for (int m4 = 0; m4 < 4; ++m4)
                #pragma unroll
                for (int r = 0; r < 4; ++r)
                    a_[m4][r] = fmaf(pT[m4][n42][r], mj4[m4][r], NBv[m4][r]);

            float mr[4];
            #pragma unroll
            for (int m4 = 0; m4 < 4; ++m4)
                mr[m4] = fmaxf(fmaxf(a_[m4][0], a_[m4][1]), fmaxf(a_[m4][2], a_[m4][3]));
            float mx = fmaxf(fmaxf(mr[0], mr[1]), fmaxf(mr[2], mr[3]));
            mx = fmaxf(mx, __shfl_xor(mx, 16)); mx = fmaxf(mx, __shfl_xor(mx, 32));

            float sr[4];
            #pragma unroll
            for (int m4 = 0; m4 < 4; ++m4) {
                #pragma unroll
                for (int r = 0; r < 4; ++r) a_[m4][r] = __expf(a_[m4][r] - mx);
                sr[m4] = (a_[m4][0] + a_[m4][1]) + (a_[m4][2] + a_[m4][3]);
            }
            float sm = (sr[0] + sr[1]) + (sr[2] + sr[3]);
            sm += __shfl_xor(sm, 16); sm += __shfl_xor(sm, 32);
            float inv = rcpf(sm);

            int i = t + 16 * (2 * w + n42);
            if (i < SEQ) {
                #pragma unroll
                for (int m4 = 0; m4 < 4; ++m4) {
                    u32x2 pw;
                    pw[0] = pk2(a_[m4][0] * inv, a_[m4][1] * inv);
                    pw[1] = pk2(a_[m4][2] * inv, a_[m4][3] * inv);
                    *(f16x4*)(wa + swzP(i, (16 * m4 + 4 * g) * 2)) = __builtin_bit_cast(f16x4, pw);
                }
            }
        }
    }

    // ================= phase F: out = P @ v (own rows; fully private) ==============
    f16x8 bv[3][2];
    #pragma unroll
    for (int nt = 0; nt < 3; ++nt)
        #pragma unroll
        for (int kt = 0; kt < 2; ++kt)
            bv[nt][kt] = *(f16x8*)(wa + swzV(t + 16 * nt, (32 * kt + 8 * g) * 2));

    f32x4 oA[2][3];
    #pragma unroll
    for (int mt2 = 0; mt2 < 2; ++mt2)
        #pragma unroll
        for (int nt = 0; nt < 3; ++nt) { f32x4 z; z[0]=0.f; z[1]=0.f; z[2]=0.f; z[3]=0.f; oA[mt2][nt] = z; }

    if (bok) {
        #pragma unroll
        for (int mt2 = 0; mt2 < 2; ++mt2) {
            int pr = 16 * (2 * w + mt2) + t; if (pr > SEQ - 1) pr = SEQ - 1;
            #pragma unroll
            for (int kt = 0; kt < 2; ++kt) {
                f16x8 ap = *(f16x8*)(wa + swzP(pr, (32 * kt + 8 * g) * 2));
                #pragma unroll
                for (int nt = 0; nt < 3; ++nt)
                    oA[mt2][nt] = __builtin_amdgcn_mfma_f32_16x16x32_f16(ap, bv[nt][kt], oA[mt2][nt], 0, 0, 0);
            }
        }

        // out -> out_lds (reuse P region, own rows): out[i][u], f16
        #pragma unroll
        for (int mt2 = 0; mt2 < 2; ++mt2)
            #pragma unroll
            for (int nt = 0; nt < 3; ++nt) {
                int u = t + 16 * nt;
                if (u < UNITD) {
                    #pragma unroll
                    for (int r = 0; r < 4; ++r) {
                        int i = 4 * g + r + 16 * (2 * w + mt2);
                        if (i < SEQ)
                            *(f16*)(wa + swzP(i, u * 2)) = (f16)oA[mt2][nt][r];
                    }
                }
            }
    }

    // ================= phase G: o2 = Wo @ out^T (+bo), own i-half =================
    f16x8 aw[3][2];
    #pragma unroll
    for (int mo = 0; mo < 3; ++mo)
        #pragma unroll
        for (int kt = 0; kt < 2; ++kt)
            aw[mo][kt] = wf[512 + (mo * 2 + kt) * 64 + lane];

    float bov[3][4], wqv[3][4];
    #pragma unroll
    for (int mo = 0; mo < 3; ++mo)
        #pragma unroll
        for (int r = 0; r < 4; ++r) {
            int o = 16 * mo + 4 * g + r; bool ok2 = (o < UNITD);
            bov[mo][r] = ok2 ? bo[o] : 0.f;
            wqv[mo][r] = ok2 ? Wq[o] : 0.f;
        }

    f32x4 o2[3][2];
    #pragma unroll
    for (int mo = 0; mo < 3; ++mo)
        #pragma unroll
        for (int n42 = 0; n42 < 2; ++n42) {
            f32x4 c;
            #pragma unroll
            for (int r = 0; r < 4; ++r) c[r] = bov[mo][r];
            o2[mo][n42] = c;
        }

    if (bok) {
        #pragma unroll
        for (int n42 = 0; n42 < 2; ++n42) {
            int br = t + 16 * (2 * w + n42); if (br > SEQ - 1) br = SEQ - 1;
            #pragma unroll
            for (int kt = 0; kt < 2; ++kt) {
                f16x8 bo_ = *(f16x8*)(wa + swzP(br, (32 * kt + 8 * g) * 2));
                #pragma unroll
                for (int mo = 0; mo < 3; ++mo)
                    o2[mo][n42] = __builtin_amdgcn_mfma_f32_16x16x32_f16(aw[mo][kt], bo_, o2[mo][n42], 0, 0, 0);
            }
        }
    }

    // ================= phase H: prob = softmax_i(out2.Wq + bq, masked), cross-wave ==
    float bq0 = bq[0];
    float tv[2];
    #pragma unroll
    for (int n42 = 0; n42 < 2; ++n42) {
        float s = 0.f;
        #pragma unroll
        for (int mo = 0; mo < 3; ++mo)
            #pragma unroll
            for (int r = 0; r < 4; ++r) s += o2[mo][n42][r] * wqv[mo][r];
        s += __shfl_xor(s, 16); s += __shfl_xor(s, 32);
        float mi = M[t + 16 * (2 * w + n42)];
        float nb = fmaf(mi, NEGBIG, -NEGBIG);
        tv[n42] = fmaf(s + bq0, mi, nb);
    }
    float mxw = fmaxf(tv[0], tv[1]);
    #pragma unroll
    for (int off = 1; off <= 8; off <<= 1) mxw = fmaxf(mxw, __shfl_xor(mxw, off));
    if (lane == 0) xmx[pr_][w] = mxw;
    __syncthreads();                                        // #3
    float mx2 = fmaxf(xmx[pr_][0], xmx[pr_][1]);
    float e0 = __expf(tv[0] - mx2);
    float e1 = __expf(tv[1] - mx2);
    float smw = e0 + e1;
    #pragma unroll
    for (int off = 1; off <= 8; off <<= 1) smw += __shfl_xor(smw, off);
    if (lane == 0) xsm[pr_][w] = smw;
    __syncthreads();                                        // #4
    float inv2 = rcpf(xsm[pr_][0] + xsm[pr_][1]);

    // ================= phase I: z[o] = sum_i prob_i * out2[i][o], cross-wave ========
    #pragma unroll
    for (int mo = 0; mo < 3; ++mo) {
        f32x4 racc;
        #pragma unroll
        for (int r = 0; r < 4; ++r) {
            float a = o2[mo][0][r] * e0;
            a = fmaf(o2[mo][1][r], e1, a);
            racc[r] = a * inv2;
        }
        #pragma unroll
        for (int off = 1; off <= 8; off <<= 1)
            #pragma unroll
            for (int r = 0; r < 4; ++r) racc[r] += __shfl_xor(racc[r], off);
        if (t == 0)
            *(f32x4*)&xz[pr_][w][16 * mo + 4 * g] = racc;
    }
    __syncthreads();                                        // #5
    if (bok && w == 0 && t == 0) {
        #pragma unroll
        for (int mo = 0; mo < 3; ++mo) {
            f32x4 z0 = *(const f32x4*)&xz[pr_][0][16 * mo + 4 * g];
            f32x4 z1 = *(const f32x4*)&xz[pr_][1][16 * mo + 4 * g];
            #pragma unroll
            for (int r = 0; r < 4; ++r) {
                int o = 16 * mo + 4 * g + r;
                if (o < UNITD) out[(size_t)b * UNITD + o] = z0[r] + z1[r];
            }
        }
    }
}

extern "C" void kernel_launch(void* const* d_in, const int* in_sizes, int n_in,
                              void* d_out, int out_size, void* d_ws, size_t ws_size,
                              hipStream_t stream) {
    const float* x    = (const float*)d_in[0];
    const float* mask = (const float*)d_in[1];
    const float* Wi   = (const float*)d_in[2];
    const float* bi   = (const float*)d_in[3];
    const float* Wo   = (const float*)d_in[4];
    const float* bo   = (const float*)d_in[5];
    const float* sq   = (const float*)d_in[6];
    const float* oq   = (const float*)d_in[7];
    const float* sk   = (const float*)d_in[8];
    const float* ok   = (const float*)d_in[9];
    const float* Wq   = (const float*)d_in[10];
    const float* bq   = (const float*)d_in[11];
    float* outp       = (float*)d_out;

    prep_kernel<<<1, 64, 0, stream>>>(Wi, Wo, (char*)d_ws);

    const int B = in_sizes[0] / (SEQ * UNITD);
    const int blocks = (B + 1) / 2;
    gau_kernel<<<blocks, 256, 0, stream>>>(x, mask, (const char*)d_ws, bi, bo,
                                           sq, oq, sk, ok, Wq, bq, outp, B);
}

// Round 13
// 173.060 us; speedup vs baseline: 1.7223x; 1.7223x over previous
//
#include <hip/hip_runtime.h>
#include <math.h>

#define SEQ 50
#define UNITD 46
#define NEGBIG 1000000000000.0f

typedef _Float16 f16;
typedef f16 f16x4 __attribute__((ext_vector_type(4)));
typedef f16 f16x8 __attribute__((ext_vector_type(8)));
typedef float f32x4 __attribute__((ext_vector_type(4)));
typedef unsigned u32x2 __attribute__((ext_vector_type(2)));
typedef unsigned u32x4 __attribute__((ext_vector_type(4)));

__device__ __forceinline__ float rcpf(float x) { return __builtin_amdgcn_rcpf(x); }
__device__ __forceinline__ unsigned pk2(float lo, float hi) {
    return __builtin_bit_cast(unsigned, __builtin_amdgcn_cvt_pkrtz(lo, hi));
}

// ---- DPP cross-lane moves (VALU pipe, no DS-pipe cost) ----
template<int CTRL>
__device__ __forceinline__ float dmov(float x) {
    int v = __builtin_bit_cast(int, x);
    return __builtin_bit_cast(float, __builtin_amdgcn_update_dpp(v, v, CTRL, 0xF, 0xF, true));
}
// butterfly reduce over each 16-lane row (valid because each step's sources are
// row-uniform at quad/octet granularity after the previous step)
__device__ __forceinline__ float dsum16(float x) {
    x += dmov<0xB1>(x);    // quad_perm(1,0,3,2): lane^1
    x += dmov<0x4E>(x);    // quad_perm(2,3,0,1): lane^2
    x += dmov<0x141>(x);   // row_half_mirror (brings other quad)
    x += dmov<0x140>(x);   // row_mirror      (brings other octet)
    return x;
}
__device__ __forceinline__ float dmax16(float x) {
    x = fmaxf(x, dmov<0xB1>(x));  x = fmaxf(x, dmov<0x4E>(x));
    x = fmaxf(x, dmov<0x141>(x)); x = fmaxf(x, dmov<0x140>(x));
    return x;
}

// ---- per-wave arena (bytes) — R10 layout ----
// [0,6400)      P tile [50][128B] swizzled; Q/K overlay it early; out tile reuses it later
// [6400,12544)  V^T [48][128B] swizzled (row=u, col=seq)
// [12544,12800) M [64] f32 (mask, zero-padded)
#define ARENA 12800
#define QOFF 0
#define KOFF 2560
#define VOFF 6400
#define MOFF 12544

__device__ __forceinline__ int swzP(int row, int colbyte) {
    return row * 128 + (colbyte ^ ((row & 7) << 4));
}
__device__ __forceinline__ int swzV(int row, int colbyte) {
    return VOFF + row * 128 + (colbyte ^ ((row & 7) << 4));
}

// ---- ws layout ----
// f16x8 units [0,512): Wi B-frags; [512,896): Wo A-frags  (bytes [0,14336))
// bytes [14336,22528): rope table float2[64*16] = (cos*0.5, sgn*sin*0.5)
#define WS_ROPE 14336

__global__ void prep_kernel(const float* __restrict__ Wi,
                            const float* __restrict__ Wo,
                            char* __restrict__ ws)
{
    f16x8* wf = (f16x8*)ws;
    const int lane = threadIdx.x & 63;
    const int g = lane >> 4, t = lane & 15;
    #pragma unroll
    for (int nt = 0; nt < 4; ++nt) {
        int c = t + 16 * nt; bool cok = c < 62;
        const float* wr = Wi + (size_t)(UNITD + (cok ? c : 0)) * UNITD;
        #pragma unroll
        for (int kt = 0; kt < 2; ++kt) {
            f16x8 f;
            #pragma unroll
            for (int jj = 0; jj < 8; ++jj) {
                int u = 32 * kt + 8 * g + jj;
                f[jj] = (f16)((cok && u < UNITD) ? wr[u] : 0.f);
            }
            wf[(nt * 2 + kt) * 64 + lane] = f;
        }
    }
    #pragma unroll
    for (int mo = 0; mo < 3; ++mo) {
        int o = 16 * mo + t; bool ook = o < UNITD;
        const float* wr = Wo + (size_t)(ook ? o : 0) * UNITD;
        #pragma unroll
        for (int kt = 0; kt < 2; ++kt) {
            f16x8 f;
            #pragma unroll
            for (int jj = 0; jj < 8; ++jj) {
                int u = 32 * kt + 8 * g + jj;
                f[jj] = (f16)((ook && u < UNITD) ? wr[u] : 0.f);
            }
            wf[512 + (mo * 2 + kt) * 64 + lane] = f;
        }
    }
    // RoPE table (0.25 QK-scale baked as 0.5 on each side); sgn=+1 d odd, -1 d even
    {
        float2* rt = (float2*)(ws + WS_ROPE);
        int seq = threadIdx.x;     // 0..63
        #pragma unroll
        for (int d = 0; d < 16; ++d) {
            float ang = (float)seq * expf(-(float)(d >> 1) * 1.1512925464970229f);
            float sn, cs;
            sincosf(ang, &sn, &cs);
            float2 v; v.x = cs * 0.5f; v.y = ((d & 1) ? sn : -sn) * 0.5f;
            rt[seq * 16 + d] = v;
        }
    }
}

__global__ __launch_bounds__(256, 3) void gau_kernel(
    const float* __restrict__ x,
    const float* __restrict__ mask,
    const char* __restrict__ ws,
    const float* __restrict__ bi,
    const float* __restrict__ bo,
    const float* __restrict__ sq,
    const float* __restrict__ oq,
    const float* __restrict__ sk,
    const float* __restrict__ ok,
    const float* __restrict__ Wq,
    const float* __restrict__ bq,
    float* __restrict__ out,
    int Btot)
{
    const int lane = threadIdx.x & 63;
    const int wid  = threadIdx.x >> 6;
    const int b    = blockIdx.x * 4 + wid;
    const int g    = lane >> 4;
    const int t    = lane & 15;

    const f16x8* wf = (const f16x8*)ws;

    __shared__ __align__(16) char smem[4 * ARENA];
    char* wa = smem + wid * ARENA;
    float* M = (float*)(wa + MOFF);

    if (b >= Btot) return;

    M[lane] = (lane < SEQ) ? mask[(size_t)b * SEQ + lane] : 0.f;

    // ================= phase B: h = silu(x @ Wi[46:108]^T + bi) =================
    f16x8 bfW[4][2];
    float biv[4];
    #pragma unroll
    for (int nt = 0; nt < 4; ++nt) {
        int c = t + 16 * nt;
        biv[nt] = (c < 62) ? bi[UNITD + c] : 0.f;
        #pragma unroll
        for (int kt = 0; kt < 2; ++kt)
            bfW[nt][kt] = wf[(nt * 2 + kt) * 64 + lane];
    }

    f32x4 hB[4][4];
    #pragma unroll
    for (int mt = 0; mt < 4; ++mt)
        #pragma unroll
        for (int nt = 0; nt < 4; ++nt) {
            f32x4 c; c[0] = biv[nt]; c[1] = biv[nt]; c[2] = biv[nt]; c[3] = biv[nt];
            hB[mt][nt] = c;
        }

    const float* xb = x + (size_t)b * (SEQ * UNITD);
    #pragma unroll
    for (int mt = 0; mt < 4; ++mt) {
        int row = 16 * mt + t; if (row > SEQ - 1) row = SEQ - 1;
        const float* xr = xb + row * UNITD;
        #pragma unroll
        for (int kt = 0; kt < 2; ++kt) {
            u32x4 axw;
            #pragma unroll
            for (int jj2 = 0; jj2 < 4; ++jj2) {
                int u = 32 * kt + 8 * g + 2 * jj2;
                float lo = 0.f, hi = 0.f;
                if (u < UNITD) { float2 w = *(const float2*)(xr + u); lo = w.x; hi = w.y; }
                axw[jj2] = pk2(lo, hi);
            }
            f16x8 ax = __builtin_bit_cast(f16x8, axw);
            #pragma unroll
            for (int nt = 0; nt < 4; ++nt)
                hB[mt][nt] = __builtin_amdgcn_mfma_f32_16x16x32_f16(ax, bfW[nt][kt], hB[mt][nt], 0, 0, 0);
        }
    }

    // ---- silu; v -> V^T LDS (f16); qk channels kept in regs ----
    float qkv[4][4];
    #pragma unroll
    for (int mt = 0; mt < 4; ++mt) {
        float s2[4], s3[4];
        #pragma unroll
        for (int nt = 0; nt < 4; ++nt) {
            float sl[4];
            #pragma unroll
            for (int r = 0; r < 4; ++r) {
                float h = hB[mt][nt][r];
                sl[r] = h * rcpf(1.f + __expf(-h));
            }
            int ucol = t + 16 * nt;
            if (nt < 3 && ucol < UNITD) {
                u32x2 pw; pw[0] = pk2(sl[0], sl[1]); pw[1] = pk2(sl[2], sl[3]);
                *(f16x4*)(wa + swzV(ucol, (16 * mt + 4 * g) * 2)) = __builtin_bit_cast(f16x4, pw);
            }
            if (nt == 2) { s2[0]=sl[0]; s2[1]=sl[1]; s2[2]=sl[2]; s2[3]=sl[3]; }
            if (nt == 3) { s3[0]=sl[0]; s3[1]=sl[1]; s3[2]=sl[2]; s3[3]=sl[3]; }
        }
        #pragma unroll
        for (int r = 0; r < 4; ++r) qkv[mt][r] = (t >= 14) ? s2[r] : s3[r];
    }

    // ================= phase C: RoPE via table; q,k -> LDS (overlaying P region) =================
    {
        f16* Q = (f16*)(wa + QOFF);
        f16* K = (f16*)(wa + KOFF);
        const float2* rt = (const float2*)(ws + WS_ROPE);
        int d = (t >= 14) ? (t - 14) : (t + 2);
        float sqd = sq[d], oqd = oq[d], skd = sk[d], okd = ok[d];
        #pragma unroll
        for (int mt = 0; mt < 4; ++mt)
            #pragma unroll
            for (int r = 0; r < 4; ++r) {
                int seq = 16 * mt + 4 * g + r;
                float2 cn = rt[seq * 16 + d];     // (cos*0.5, sgn*sin*0.5)
                float qv = qkv[mt][r] * sqd + oqd;
                float kv = qkv[mt][r] * skd + okd;
                float qp = dmov<0xB1>(qv);        // partner (lane^1) via DPP, was shfl
                float kp = dmov<0xB1>(kv);
                Q[seq * 20 + d] = (f16)(qv * cn.x + qp * cn.y);
                K[seq * 20 + d] = (f16)(kv * cn.x + kp * cn.y);
            }
    }

    // ================= phase D: P^T = q'k'^T (0.25 baked), masked, softmax =================
    f16x4 ak[4], bq_[4];
    #pragma unroll
    for (int m4 = 0; m4 < 4; ++m4) ak[m4]  = *(f16x4*)(wa + KOFF + (16 * m4 + t) * 40 + 8 * g);
    #pragma unroll
    for (int n4 = 0; n4 < 4; ++n4) bq_[n4] = *(f16x4*)(wa + QOFF + (16 * n4 + t) * 40 + 8 * g);

    f32x4 pT[4][4];
    #pragma unroll
    for (int m4 = 0; m4 < 4; ++m4)
        #pragma unroll
        for (int n4 = 0; n4 < 4; ++n4) {
            f32x4 z; z[0]=0.f; z[1]=0.f; z[2]=0.f; z[3]=0.f;
            pT[m4][n4] = __builtin_amdgcn_mfma_f32_16x16x16f16(ak[m4], bq_[n4], z, 0, 0, 0);
        }

    f32x4 mj4[4];
    float NBv[4][4];
    #pragma unroll
    for (int m4 = 0; m4 < 4; ++m4) {
        mj4[m4] = *(f32x4*)(M + 16 * m4 + 4 * g);
        #pragma unroll
        for (int r = 0; r < 4; ++r)
            NBv[m4][r] = fmaf(mj4[m4][r], NEGBIG, -NEGBIG);    // (m-1)*BIG
    }

    // Q/K region is dead once pT is computed; P writes below overwrite it.
    #pragma unroll
    for (int n4 = 0; n4 < 4; ++n4) {
        float a_[4][4];
        #pragma unroll
        for (int m4 = 0; m4 < 4; ++m4)
            #pragma unroll
            for (int r = 0; r < 4; ++r)
                a_[m4][r] = fmaf(pT[m4][n4][r], mj4[m4][r], NBv[m4][r]);

        float mr[4];
        #pragma unroll
        for (int m4 = 0; m4 < 4; ++m4)
            mr[m4] = fmaxf(fmaxf(a_[m4][0], a_[m4][1]), fmaxf(a_[m4][2], a_[m4][3]));
        float mx = fmaxf(fmaxf(mr[0], mr[1]), fmaxf(mr[2], mr[3]));
        mx = fmaxf(mx, __shfl_xor(mx, 16)); mx = fmaxf(mx, __shfl_xor(mx, 32));

        float sr[4];
        #pragma unroll
        for (int m4 = 0; m4 < 4; ++m4) {
            #pragma unroll
            for (int r = 0; r < 4; ++r) a_[m4][r] = __expf(a_[m4][r] - mx);
            sr[m4] = (a_[m4][0] + a_[m4][1]) + (a_[m4][2] + a_[m4][3]);
        }
        float sm = (sr[0] + sr[1]) + (sr[2] + sr[3]);
        sm += __shfl_xor(sm, 16); sm += __shfl_xor(sm, 32);
        float inv = rcpf(sm);

        int i = t + 16 * n4;
        if (i < SEQ) {
            #pragma unroll
            for (int m4 = 0; m4 < 4; ++m4) {
                u32x2 pw;
                pw[0] = pk2(a_[m4][0] * inv, a_[m4][1] * inv);
                pw[1] = pk2(a_[m4][2] * inv, a_[m4][3] * inv);
                *(f16x4*)(wa + swzP(i, (16 * m4 + 4 * g) * 2)) = __builtin_bit_cast(f16x4, pw);
            }
        }
    }

    // ================= phase F: out = P @ v =================
    f16x8 bv[3][2];
    #pragma unroll
    for (int nt = 0; nt < 3; ++nt)
        #pragma unroll
        for (int kt = 0; kt < 2; ++kt)
            bv[nt][kt] = *(f16x8*)(wa + swzV(t + 16 * nt, (32 * kt + 8 * g) * 2));

    f32x4 oA[4][3];
    #pragma unroll
    for (int mt = 0; mt < 4; ++mt)
        #pragma unroll
        for (int nt = 0; nt < 3; ++nt) { f32x4 z; z[0]=0.f; z[1]=0.f; z[2]=0.f; z[3]=0.f; oA[mt][nt] = z; }

    #pragma unroll
    for (int mt = 0; mt < 4; ++mt) {
        int pr = 16 * mt + t; if (pr > SEQ - 1) pr = SEQ - 1;
        #pragma unroll
        for (int kt = 0; kt < 2; ++kt) {
            f16x8 ap = *(f16x8*)(wa + swzP(pr, (32 * kt + 8 * g) * 2));
            #pragma unroll
            for (int nt = 0; nt < 3; ++nt)
                oA[mt][nt] = __builtin_amdgcn_mfma_f32_16x16x32_f16(ap, bv[nt][kt], oA[mt][nt], 0, 0, 0);
        }
    }

    // out -> out_lds (reuse P region): out[i = 4g+r+16mt][u = t+16nt], f16
    #pragma unroll
    for (int mt = 0; mt < 4; ++mt)
        #pragma unroll
        for (int nt = 0; nt < 3; ++nt) {
            int u = t + 16 * nt;
            if (u < UNITD) {
                #pragma unroll
                for (int r = 0; r < 4; ++r) {
                    int i = 4 * g + r + 16 * mt;
                    if (i < SEQ)
                        *(f16*)(wa + swzP(i, u * 2)) = (f16)oA[mt][nt][r];
                }
            }
        }

    // ================= phase G: out2^T = Wo @ out^T (+bo as C-init) =================
    f16x8 aw[3][2];
    #pragma unroll
    for (int mo = 0; mo < 3; ++mo)
        #pragma unroll
        for (int kt = 0; kt < 2; ++kt)
            aw[mo][kt] = wf[512 + (mo * 2 + kt) * 64 + lane];

    float bov[3][4], wqv[3][4];
    #pragma unroll
    for (int mo = 0; mo < 3; ++mo)
        #pragma unroll
        for (int r = 0; r < 4; ++r) {
            int o = 16 * mo + 4 * g + r; bool ok2 = (o < UNITD);
            bov[mo][r] = ok2 ? bo[o] : 0.f;
            wqv[mo][r] = ok2 ? Wq[o] : 0.f;
        }

    f32x4 o2[3][4];
    #pragma unroll
    for (int mo = 0; mo < 3; ++mo)
        #pragma unroll
        for (int n4 = 0; n4 < 4; ++n4) {
            f32x4 c;
            #pragma unroll
            for (int r = 0; r < 4; ++r) c[r] = bov[mo][r];
            o2[mo][n4] = c;
        }

    #pragma unroll
    for (int n4 = 0; n4 < 4; ++n4) {
        int br = t + 16 * n4; if (br > SEQ - 1) br = SEQ - 1;
        #pragma unroll
        for (int kt = 0; kt < 2; ++kt) {
            f16x8 bo_ = *(f16x8*)(wa + swzP(br, (32 * kt + 8 * g) * 2));
            #pragma unroll
            for (int mo = 0; mo < 3; ++mo)
                o2[mo][n4] = __builtin_amdgcn_mfma_f32_16x16x32_f16(aw[mo][kt], bo_, o2[mo][n4], 0, 0, 0);
        }
    }

    // ================= phase H: prob = softmax_i(out2 . Wq + bq, masked) =================
    float bq0 = bq[0];
    float tv[4]; float mx2 = -INFINITY;
    #pragma unroll
    for (int n4 = 0; n4 < 4; ++n4) {
        float s = 0.f;
        #pragma unroll
        for (int mo = 0; mo < 3; ++mo)
            #pragma unroll
            for (int r = 0; r < 4; ++r) s += o2[mo][n4][r] * wqv[mo][r];
        s += __shfl_xor(s, 16); s += __shfl_xor(s, 32);
        float mi = M[t + 16 * n4];
        float nb = fmaf(mi, NEGBIG, -NEGBIG);
        tv[n4] = fmaf(s + bq0, mi, nb);
        mx2 = fmaxf(mx2, tv[n4]);
    }
    mx2 = dmax16(mx2);                                   // was 4x shfl tree
    float sm2 = 0.f;
    #pragma unroll
    for (int n4 = 0; n4 < 4; ++n4) { float e = __expf(tv[n4] - mx2); tv[n4] = e; sm2 += e; }
    sm2 = dsum16(sm2);                                   // was 4x shfl tree
    float inv2 = rcpf(sm2);

    // ================= phase I: result[o] = sum_i out2[i][o] * prob[i] =================
    #pragma unroll
    for (int mo = 0; mo < 3; ++mo) {
        float racc[4];
        #pragma unroll
        for (int r = 0; r < 4; ++r) {
            float a = 0.f;
            #pragma unroll
            for (int n4 = 0; n4 < 4; ++n4) a += o2[mo][n4][r] * tv[n4];
            racc[r] = dsum16(a);                         // was 4x shfl tree per r
        }
        if (t == 0) {
            #pragma unroll
            for (int r = 0; r < 4; ++r) {
                int o = 16 * mo + 4 * g + r;
                if (o < UNITD) out[(size_t)b * UNITD + o] = racc[r] * inv2;
            }
        }
    }
}

extern "C" void kernel_launch(void* const* d_in, const int* in_sizes, int n_in,
                              void* d_out, int out_size, void* d_ws, size_t ws_size,
                              hipStream_t stream) {
    const float* x    = (const float*)d_in[0];
    const float* mask = (const float*)d_in[1];
    const float* Wi   = (const float*)d_in[2];
    const float* bi   = (const float*)d_in[3];
    const float* Wo   = (const float*)d_in[4];
    const float* bo   = (const float*)d_in[5];
    const float* sq   = (const float*)d_in[6];
    const float* oq   = (const float*)d_in[7];
    const float* sk   = (const float*)d_in[8];
    const float* ok   = (const float*)d_in[9];
    const float* Wq   = (const float*)d_in[10];
    const float* bq   = (const float*)d_in[11];
    float* outp       = (float*)d_out;

    prep_kernel<<<1, 64, 0, stream>>>(Wi, Wo, (char*)d_ws);

    const int B = in_sizes[0] / (SEQ * UNITD);
    const int blocks = (B + 3) / 4;
    gau_kernel<<<blocks, 256, 0, stream>>>(x, mask, (const char*)d_ws, bi, bo,
                                           sq, oq, sk, ok, Wq, bq, outp, B);
}